// Round 13
// baseline (411.975 us; speedup 1.0000x reference)
//
#include <hip/hip_runtime.h>
#include <hip/hip_bf16.h>

typedef __hip_bfloat16 bf16;
typedef __attribute__((ext_vector_type(8))) short  s16x8;  // 8 bf16 = 4 VGPR (MFMA A/B frag)
typedef __attribute__((ext_vector_type(4))) float  f32x4;  // MFMA C/D frag

static constexpr int S    = 2048;
static constexpr int D    = 4096;
static constexpr int H    = 32;
static constexpr int QL   = 1536;
static constexpr int KVL  = 512;
static constexpr int NOPE = 128;
static constexpr int ROPE = 64;
static constexpr int QKH  = 192;
static constexpr int VH   = 128;
static constexpr int CAT  = 576;
static constexpr int CAT2 = 192;    // absorbed head dim: 128 nope + 64 rope
static constexpr int NCAT = 2112;   // QL + CAT (merged q_a/kv_a GEMM width)
static constexpr float EPS = 1e-6f;

__device__ __forceinline__ void stf(float* p, float v){ *p = v; }
__device__ __forceinline__ void stf(bf16* p, float v){ *p = __float2bfloat16(v); }

__device__ __forceinline__ float wave_sum(float v){
#pragma unroll
  for (int off = 32; off; off >>= 1) v += __shfl_xor(v, off, 64);
  return v;
}

__device__ __forceinline__ void gload16(const bf16* src, unsigned short* dst){
  __builtin_amdgcn_global_load_lds(
      (const __attribute__((address_space(1))) unsigned int*)src,
      (__attribute__((address_space(3))) unsigned int*)dst, 16, 0, 0);
}

// ---------------------------------------------------------------------------
// f32 -> bf16 cast, vectorized
// ---------------------------------------------------------------------------
__global__ __launch_bounds__(256)
void cast_kernel(const float* __restrict__ in, bf16* __restrict__ out, long long n4)
{
  long long i = (long long)blockIdx.x * 256 + threadIdx.x;
  const long long stride = (long long)gridDim.x * 256;
  for (; i < n4; i += stride) {
    float4 v = ((const float4*)in)[i];
    union { bf16 b[4]; uint2 u; } t;
    t.b[0] = __float2bfloat16(v.x); t.b[1] = __float2bfloat16(v.y);
    t.b[2] = __float2bfloat16(v.z); t.b[3] = __float2bfloat16(v.w);
    *(uint2*)(out + i * 4) = t.u;
  }
}

// ---------------------------------------------------------------------------
// transpose-cast: in f32 [batch][R][C] -> out bf16 [batch][C][R]. 32x32 tiles.
// ---------------------------------------------------------------------------
__global__ __launch_bounds__(256)
void tcast_kernel(const float* __restrict__ in, bf16* __restrict__ out, int R, int C)
{
  const long long b = blockIdx.z;
  in  += b * (long long)R * C;
  out += b * (long long)R * C;
  const int c0 = blockIdx.x * 32, r0 = blockIdx.y * 32;
  __shared__ float t[32][33];
  const int tx = threadIdx.x & 31, ty = threadIdx.x >> 5;
#pragma unroll
  for (int p = 0; p < 4; p++)
    t[ty + p * 8][tx] = in[(long long)(r0 + ty + p * 8) * C + c0 + tx];
  __syncthreads();
#pragma unroll
  for (int p = 0; p < 4; p++)
    out[(long long)(c0 + ty + p * 8) * R + r0 + tx] = __float2bfloat16(t[tx][ty + p * 8]);
}

// ---------------------------------------------------------------------------
// MFMA GEMM v3 (verified R10-R12): 256x256 tile, BK=64, 8 waves, counted-vmcnt
// deep pipeline.  Raw s_barrier + s_waitcnt vmcnt(8) keeps the NEXT tile's 8
// global_load_lds in flight ACROSS the barrier.
// EPI=0: C[row*ldc+col].  EPI=1: ABSORB epilogue (verified R11) -- col<4096
// writes k2[h=col>>7][row][col&127], col>=4096 writes kv_vT[(col-4096)*S+row].
// ---------------------------------------------------------------------------
template<typename TC, int EPI = 0>
__global__ __launch_bounds__(512, 2)
void mgemm3(const bf16* __restrict__ A, const bf16* __restrict__ B, TC* __restrict__ C,
            TC* __restrict__ C2,
            int M, int N, int K, int lda, int ldb, int ldc,
            long long sA, long long sB, long long sC)
{
  A += (long long)blockIdx.z * sA;
  B += (long long)blockIdx.z * sB;
  C += (long long)blockIdx.z * sC;
  __shared__ unsigned short As[2][256 * 64];   // 2 x 32 KB
  __shared__ unsigned short Bs[2][256 * 64];   // 2 x 32 KB
  const int tid = threadIdx.x;
  const int w = tid >> 6;
  const int lane = tid & 63;
  const int l15 = lane & 15, g = lane >> 4;
  const int wr = w >> 2, wc = w & 3;
  const int m0 = blockIdx.y * 256, n0 = blockIdx.x * 256;

  const bf16* asrc[4];
  const bf16* bsrc[4];
#pragma unroll
  for (int j = 0; j < 4; j++) {
    const int f = j * 512 + tid;
    const int row = f >> 3;                 // 0..255
    const int cg = ((f & 7) ^ (row & 7)) * 8;
    asrc[j] = A + (long long)(m0 + row) * lda + cg;
    int br = n0 + row; if (br >= N) br = N - 1;
    bsrc[j] = B + (long long)br * ldb + cg;
  }

  auto stage = [&](int b, int k0) {
#pragma unroll
    for (int j = 0; j < 4; j++) {
      gload16(asrc[j] + k0, &As[b][(j * 512 + w * 64) * 8]);
      gload16(bsrc[j] + k0, &Bs[b][(j * 512 + w * 64) * 8]);
    }
  };

  f32x4 acc[8][4];
#pragma unroll
  for (int i = 0; i < 8; i++)
#pragma unroll
    for (int j = 0; j < 4; j++) acc[i][j] = (f32x4){0.f, 0.f, 0.f, 0.f};

  const int ntk = K >> 6;
  stage(0, 0);

  for (int t = 0; t < ntk; ++t) {
    const int b = t & 1;
    asm volatile("" ::: "memory");
    __builtin_amdgcn_s_barrier();
    if (t + 1 < ntk) {
      stage(b ^ 1, (t + 1) << 6);
      asm volatile("s_waitcnt vmcnt(8)" ::: "memory");
    } else {
      asm volatile("s_waitcnt vmcnt(0)" ::: "memory");
    }
    __builtin_amdgcn_s_barrier();
    asm volatile("" ::: "memory");

    const unsigned short* Ab = &As[b][(wr * 128 + l15) * 64];
    const unsigned short* Bb = &Bs[b][(wc * 64 + l15) * 64];
    const int swz = l15 & 7;
#pragma unroll
    for (int kk = 0; kk < 2; ++kk) {
      const int co = (((kk * 4 + g) ^ swz) * 8);
      s16x8 a[8], bb[4];
#pragma unroll
      for (int mt = 0; mt < 8; mt++)
        a[mt] = *(const s16x8*)(Ab + mt * 1024 + co);
#pragma unroll
      for (int nt = 0; nt < 4; nt++)
        bb[nt] = *(const s16x8*)(Bb + nt * 1024 + co);
      __builtin_amdgcn_s_setprio(1);
#pragma unroll
      for (int mt = 0; mt < 8; mt++)
#pragma unroll
        for (int nt = 0; nt < 4; nt++)
          acc[mt][nt] = __builtin_amdgcn_mfma_f32_16x16x32_bf16(a[mt], bb[nt], acc[mt][nt], 0, 0, 0);
      __builtin_amdgcn_s_setprio(0);
    }
  }

#pragma unroll
  for (int mt = 0; mt < 8; mt++)
#pragma unroll
    for (int nt = 0; nt < 4; nt++) {
      const int col = n0 + wc * 64 + nt * 16 + l15;
      const int row0 = m0 + wr * 128 + mt * 16 + g * 4;
      if constexpr (EPI == 0) {
        if (col < N) {
#pragma unroll
          for (int r = 0; r < 4; r++)
            stf(C + (long long)(row0 + r) * ldc + col, acc[mt][nt][r]);
        }
      } else {
        if (col < H * NOPE) {               // key-absorb -> k2[h][row][n]
          TC* dst = C + ((long long)(col >> 7) * S + row0) * CAT2 + (col & 127);
#pragma unroll
          for (int r = 0; r < 4; r++)
            stf(dst + (long long)r * CAT2, acc[mt][nt][r]);
        } else {                             // value-absorb -> kv_vT[c'][row]
          TC* dst = C2 + (long long)(col - H * NOPE) * S + row0;
#pragma unroll
          for (int r = 0; r < 4; r++)
            stf(dst + r, acc[mt][nt][r]);
        }
      }
    }
}

// ---------------------------------------------------------------------------
// MFMA GEMM v4: 256x128 tile, BK=64, 8 waves (4x2), same counted-vmcnt
// skeleton as verified mgemm3 (vmcnt(6): 4 A + 2 B loads/thread/tile).
// LDS 96 KB -> 1 block/CU.  Gives 2x the tiles of 256^2 for mid-size N:
//   out GEMM  (N=4096): 256 tiles = 1/CU at z=1 -> no K-split, no add pass.
//   q_b GEMM  (N=6144): 384 tiles = 1.5/CU.
// EPI=0: C[row*ldc+col] (col<N guarded).
// EPI=2: q2 ROPE epilogue -- N=6144=H*192; each wave's 64-col block lies
//   wholly in one head (192=3*64) and is wholly nope or wholly rope; the rope
//   pair (r, r^32) is acc[mt][nt] / acc[mt][nt^2] IN-REGISTER.  Applies rope
//   on f32 accumulators and writes q2[h][row][192] directly (replaces the
//   q_raw round-trip + qprep kernel).
// ---------------------------------------------------------------------------
template<typename TC, int EPI = 0>
__global__ __launch_bounds__(512, 1)
void mgemm4(const bf16* __restrict__ A, const bf16* __restrict__ B, TC* __restrict__ C,
            const float* __restrict__ cosp, const float* __restrict__ sinp,
            int M, int N, int K, int lda, int ldb, int ldc)
{
  __shared__ unsigned short As[2][256 * 64];   // 2 x 32 KB
  __shared__ unsigned short Bs[2][128 * 64];   // 2 x 16 KB
  const int tid = threadIdx.x;
  const int w = tid >> 6;
  const int lane = tid & 63;
  const int l15 = lane & 15, g = lane >> 4;
  const int wr = w >> 1, wc = w & 1;          // 4 x 2 wave grid
  const int m0 = blockIdx.y * 256, n0 = blockIdx.x * 128;

  // staging: A 2048 chunks (4/thread), B 1024 chunks (2/thread); src pre-swz
  const bf16* asrc[4];
  const bf16* bsrc[2];
#pragma unroll
  for (int j = 0; j < 4; j++) {
    const int f = j * 512 + tid;
    const int row = f >> 3;
    const int cg = ((f & 7) ^ (row & 7)) * 8;
    asrc[j] = A + (long long)(m0 + row) * lda + cg;
  }
#pragma unroll
  for (int j = 0; j < 2; j++) {
    const int f = j * 512 + tid;
    const int row = f >> 3;                  // 0..127
    const int cg = ((f & 7) ^ (row & 7)) * 8;
    int br = n0 + row; if (br >= N) br = N - 1;
    bsrc[j] = B + (long long)br * ldb + cg;
  }

  auto stage = [&](int b, int k0) {
#pragma unroll
    for (int j = 0; j < 4; j++)
      gload16(asrc[j] + k0, &As[b][(j * 512 + w * 64) * 8]);
#pragma unroll
    for (int j = 0; j < 2; j++)
      gload16(bsrc[j] + k0, &Bs[b][(j * 512 + w * 64) * 8]);
  };

  f32x4 acc[4][4];
#pragma unroll
  for (int i = 0; i < 4; i++)
#pragma unroll
    for (int j = 0; j < 4; j++) acc[i][j] = (f32x4){0.f, 0.f, 0.f, 0.f};

  const int ntk = K >> 6;
  stage(0, 0);

  for (int t = 0; t < ntk; ++t) {
    const int b = t & 1;
    asm volatile("" ::: "memory");
    __builtin_amdgcn_s_barrier();
    if (t + 1 < ntk) {
      stage(b ^ 1, (t + 1) << 6);
      asm volatile("s_waitcnt vmcnt(6)" ::: "memory");   // tile t's 6 landed
    } else {
      asm volatile("s_waitcnt vmcnt(0)" ::: "memory");
    }
    __builtin_amdgcn_s_barrier();
    asm volatile("" ::: "memory");

    const unsigned short* Ab = &As[b][(wr * 64 + l15) * 64];
    const unsigned short* Bb = &Bs[b][(wc * 64 + l15) * 64];
    const int swz = l15 & 7;
#pragma unroll
    for (int kk = 0; kk < 2; ++kk) {
      const int co = (((kk * 4 + g) ^ swz) * 8);
      s16x8 a[4], bb[4];
#pragma unroll
      for (int mt = 0; mt < 4; mt++)
        a[mt] = *(const s16x8*)(Ab + mt * 1024 + co);
#pragma unroll
      for (int nt = 0; nt < 4; nt++)
        bb[nt] = *(const s16x8*)(Bb + nt * 1024 + co);
      __builtin_amdgcn_s_setprio(1);
#pragma unroll
      for (int mt = 0; mt < 4; mt++)
#pragma unroll
        for (int nt = 0; nt < 4; nt++)
          acc[mt][nt] = __builtin_amdgcn_mfma_f32_16x16x32_bf16(a[mt], bb[nt], acc[mt][nt], 0, 0, 0);
      __builtin_amdgcn_s_setprio(0);
    }
  }

  if constexpr (EPI == 0) {
#pragma unroll
    for (int mt = 0; mt < 4; mt++)
#pragma unroll
      for (int nt = 0; nt < 4; nt++) {
        const int col = n0 + wc * 64 + nt * 16 + l15;
        if (col < N) {
          const int row0 = m0 + wr * 64 + mt * 16 + g * 4;
#pragma unroll
          for (int r = 0; r < 4; r++)
            stf(C + (long long)(row0 + r) * ldc + col, acc[mt][nt][r]);
        }
      }
  } else {
    // ROPE epilogue: wave's 64-block = blk; head hh = blk/3; dbase in {0,64,128}
    const int blk = blockIdx.x * 2 + wc;
    const int hh = blk / 3;
    const int dbase = (blk % 3) * 64;
    const bool isrope = (dbase == 128);
#pragma unroll
    for (int mt = 0; mt < 4; mt++) {
      const int row0 = m0 + wr * 64 + mt * 16 + g * 4;
#pragma unroll
      for (int nt = 0; nt < 4; nt++) {
        if (!isrope) {
          const int d = dbase + nt * 16 + l15;
#pragma unroll
          for (int r = 0; r < 4; r++)
            stf((bf16*)C + ((long long)hh * S + row0 + r) * CAT2 + d, acc[mt][nt][r]);
        } else {
          const int rr = nt * 16 + l15;     // rope dim 0..63
#pragma unroll
          for (int r = 0; r < 4; r++) {
            const int srow = row0 + r;
            const float x   = acc[mt][nt][r];
            const float xp  = acc[mt][nt ^ 2][r];     // col +/- 32, in-register
            const float rot = (rr < 32) ? -xp : xp;
            stf((bf16*)C + ((long long)hh * S + srow) * CAT2 + NOPE + rr,
                x * cosp[srow * ROPE + rr] + rot * sinp[srow * ROPE + rr]);
          }
        }
      }
    }
  }
}

// ---------------------------------------------------------------------------
// RMSNorm over SUM of FOUR K-split partials (z-stride poff), N = QL fixed.
// ---------------------------------------------------------------------------
__global__ __launch_bounds__(256)
void rmsnorm_cast_kernel(const float* __restrict__ x, const float* __restrict__ g,
                         bf16* __restrict__ out, int ldx, long long poff)
{
  const int row = blockIdx.x;
  const float* xr = x + (long long)row * ldx;
  float v[6];
  float ss = 0.f;
#pragma unroll
  for (int k = 0; k < 6; k++) {
    const int c = threadIdx.x + (k << 8);
    const float t = xr[c] + xr[c + poff] + xr[c + 2 * poff] + xr[c + 3 * poff];
    v[k] = t; ss += t * t;
  }
  __shared__ float red[4];
  ss = wave_sum(ss);
  if ((threadIdx.x & 63) == 0) red[threadIdx.x >> 6] = ss;
  __syncthreads();
  const float inv = rsqrtf((red[0] + red[1] + red[2] + red[3]) / (float)QL + EPS);
#pragma unroll
  for (int k = 0; k < 6; k++) {
    const int c = threadIdx.x + (k << 8);
    out[(long long)row * QL + c] = __float2bfloat16(v[k] * inv * g[c]);
  }
}

// ---------------------------------------------------------------------------
// kv post over SUM of FOUR K-split partials (row stride ldr, z-stride poff).
// ---------------------------------------------------------------------------
__global__ __launch_bounds__(256)
void kvpost_kernel(const float* __restrict__ kv_raw, const float* __restrict__ g,
                   const float* __restrict__ cosp, const float* __restrict__ sinp,
                   bf16* __restrict__ kv_cat, int ldr, long long poff)
{
  const int s = blockIdx.x;
  const float* row = kv_raw + (long long)s * ldr;
  float v[2];
  float ss = 0.f;
#pragma unroll
  for (int k = 0; k < 2; k++) {
    const int c = threadIdx.x + (k << 8);
    const float t = row[c] + row[c + poff] + row[c + 2 * poff] + row[c + 3 * poff];
    v[k] = t; ss += t * t;
  }
  __shared__ float red[4];
  float ws_ = wave_sum(ss);
  if ((threadIdx.x & 63) == 0) red[threadIdx.x >> 6] = ws_;
  __syncthreads();
  const float inv = rsqrtf((red[0] + red[1] + red[2] + red[3]) / (float)KVL + EPS);
#pragma unroll
  for (int k = 0; k < 2; k++) {
    const int c = threadIdx.x + (k << 8);
    kv_cat[(long long)s * CAT + c] = __float2bfloat16(v[k] * inv * g[c]);
  }
  if (threadIdx.x < 64) {
    const int r = threadIdx.x;
    const int c = KVL + r;
    const float x = row[c] + row[c + poff] + row[c + 2 * poff] + row[c + 3 * poff];
    const float xp = __shfl_xor(x, 32, 64);
    const float rot = (r < 32) ? -xp : xp;
    kv_cat[(long long)s * CAT + KVL + r] =
        __float2bfloat16(x * cosp[s * ROPE + r] + rot * sinp[s * ROPE + r]);
  }
}

// ---------------------------------------------------------------------------
// k rope broadcast: k2[h][s][128+r] = kv_cat[s][512+r] for all heads
// ---------------------------------------------------------------------------
__global__ __launch_bounds__(256)
void krope_bcast(const bf16* __restrict__ kv_cat, bf16* __restrict__ k2)
{
  const int s = blockIdx.x;
  const int h = threadIdx.x >> 3;
  const int i = (threadIdx.x & 7) * 8;
  *(uint4*)(k2 + ((long long)h * S + s) * CAT2 + NOPE + i) =
      *(const uint4*)(kv_cat + (long long)s * CAT + KVL + i);
}

// ---------------------------------------------------------------------------
// MFMA flash attention v13 (verified R4-R12, 81 us): key+value absorbed,
// head dim 192, cheap overflow-detect softmax, stage-before-compute +
// single __syncthreads skeleton.
// ---------------------------------------------------------------------------
__global__ __launch_bounds__(512, 2)
void attn_mfma13(const bf16* __restrict__ q2, const bf16* __restrict__ k2,
                 const bf16* __restrict__ kv_vT, bf16* __restrict__ ctx)
{
  __shared__ unsigned short kkl[2][32 * CAT2];  // 2 x 12,288 B  K tiles (swizzled)
  __shared__ unsigned short vtl[2][128 * 32];   // 2 x  8,192 B  V^T tiles (swizzled)
  __shared__ unsigned short ps[8][16][40];      // 10,240 B per-wave P transpose
  const int tid = threadIdx.x;
  const int bid = blockIdx.x;
  const int h  = bid & 31;
  const int qb = 15 - (bid >> 5);               // heavy blocks dispatched first
  const int w = tid >> 6, lane = tid & 63;
  const int l15 = lane & 15, g = lane >> 4;
  const int wq0 = qb * 128 + w * 16;
  const int rbase = g * 4;
  const float scale = 0.07216878364870322f;     // 1/sqrt(192)

  const bf16* ksrc[2];
#pragma unroll
  for (int j = 0; j < 2; j++) {
    const int f  = j * 512 + ((j == 1) ? (tid & 255) : tid);
    const int r  = f / 24;
    const int cg = ((f % 24) << 4) ^ ((r & 7) << 4);
    ksrc[j] = k2 + ((long long)h * S + r) * CAT2 + (cg >> 1);
  }
  const int vc = tid >> 2;
  const bf16* vsrc = kv_vT + (long long)h * VH * S + (long long)vc * S
                   + (((tid & 3) ^ ((vc >> 1) & 3)) * 8);

  auto stage = [&](int buf, int kbase) {
    gload16(ksrc[0] + (long long)kbase * CAT2, &kkl[buf][(w * 64) * 8]);
    if (tid < 256)
      gload16(ksrc[1] + (long long)kbase * CAT2, &kkl[buf][(512 + w * 64) * 8]);
    gload16(vsrc + kbase, &vtl[buf][(w * 64) * 8]);
  };

  s16x8 qf[6];
  const bf16* qp = q2 + ((long long)h * S + (wq0 + l15)) * CAT2 + g * 8;
#pragma unroll
  for (int ch = 0; ch < 6; ch++) qf[ch] = *(const s16x8*)(qp + ch * 32);

  s16x8 ones;
#pragma unroll
  for (int i = 0; i < 8; i++) ones[i] = (short)0x3F80;

  f32x4 acc[8];
#pragma unroll
  for (int nt = 0; nt < 8; nt++) acc[nt] = (f32x4){0.f, 0.f, 0.f, 0.f};
  f32x4 accl = (f32x4){0.f, 0.f, 0.f, 0.f};
  float mrow[4];
#pragma unroll
  for (int r = 0; r < 4; r++) mrow[r] = -3e38f;

  stage(0, 0);
  __syncthreads();

  const int ntb = 4 * qb + 4;
  int buf = 0;
  for (int t = 0; t < ntb; t++) {
    const int kbase = t * 32;
    if (t + 1 < ntb) stage(buf ^ 1, kbase + 32);   // overlap with compute(t)
    if (kbase <= wq0 + 15) {
      f32x4 st0 = (f32x4){0.f,0.f,0.f,0.f}, st1 = (f32x4){0.f,0.f,0.f,0.f};
      const unsigned short* kb0 = &kkl[buf][l15 * CAT2];
      const int rsw = (l15 & 7) << 4;
#pragma unroll
      for (int ch = 0; ch < 6; ch++) {
        const int cb = ((ch * 64 + g * 16) ^ rsw) >> 1;
        s16x8 b0 = *(const s16x8*)(kb0 + cb);
        s16x8 b1 = *(const s16x8*)(kb0 + 16 * CAT2 + cb);
        st0 = __builtin_amdgcn_mfma_f32_16x16x32_bf16(qf[ch], b0, st0, 0, 0, 0);
        st1 = __builtin_amdgcn_mfma_f32_16x16x32_bf16(qf[ch], b1, st1, 0, 0, 0);
      }
      float p0v[4], p1v[4];
      float pmax = 0.f;
#pragma unroll
      for (int r = 0; r < 4; r++) {
        const int qg = wq0 + rbase + r;
        const bool v0 = (kbase + l15) <= qg, v1 = (kbase + 16 + l15) <= qg;
        const float s0 = st0[r] * scale, s1 = st1[r] * scale;
        const float p0 = v0 ? __expf(s0 - mrow[r]) : 0.f;
        const float p1 = v1 ? __expf(s1 - mrow[r]) : 0.f;
        p0v[r] = p0; p1v[r] = p1;
        pmax = fmaxf(pmax, fmaxf(p0, p1));
      }
      if (__builtin_expect(__any(pmax > 2981.0f), 0)) {   // rare: growth > ~8
#pragma unroll
        for (int r = 0; r < 4; r++) {
          const int qg = wq0 + rbase + r;
          const bool v0 = (kbase + l15) <= qg, v1 = (kbase + 16 + l15) <= qg;
          const float s0 = st0[r] * scale, s1 = st1[r] * scale;
          float tmax = fmaxf(v0 ? s0 : -3e38f, v1 ? s1 : -3e38f);
#pragma unroll
          for (int off = 8; off; off >>= 1) tmax = fmaxf(tmax, __shfl_xor(tmax, off, 64));
          if (tmax > mrow[r] + 8.0f) {
            const float corr = __expf(mrow[r] - tmax);    // 0 on first tile
            mrow[r] = tmax;
#pragma unroll
            for (int nt = 0; nt < 8; nt++) acc[nt][r] *= corr;
            accl[r] *= corr;
            p0v[r] = v0 ? __expf(s0 - mrow[r]) : 0.f;
            p1v[r] = v1 ? __expf(s1 - mrow[r]) : 0.f;
          }
        }
      }
#pragma unroll
      for (int r = 0; r < 4; r++) {
        union { bf16 b; unsigned short u; } c0, c1;
        c0.b = __float2bfloat16(p0v[r]); c1.b = __float2bfloat16(p1v[r]);
        ps[w][rbase + r][l15]      = c0.u;
        ps[w][rbase + r][16 + l15] = c1.u;
      }
      asm volatile("" ::: "memory");   // order ps stores before reads (per-wave)
      s16x8 pa = *(const s16x8*)&ps[w][l15][g * 8];
      const unsigned short* vt = &vtl[buf][l15 * 32 + ((g * 8) ^ (((l15 >> 1) & 3) * 8))];
#pragma unroll
      for (int nt = 0; nt < 8; nt++) {
        s16x8 bv = *(const s16x8*)(vt + nt * 512);
        acc[nt] = __builtin_amdgcn_mfma_f32_16x16x32_bf16(pa, bv, acc[nt], 0, 0, 0);
      }
      accl = __builtin_amdgcn_mfma_f32_16x16x32_bf16(pa, ones, accl, 0, 0, 0);
    }
    __syncthreads();   // drains stage(t+1) loads + all waves done with buf
    buf ^= 1;
  }

#pragma unroll
  for (int r = 0; r < 4; r++) {
    const float inv = 1.f / accl[r];
    bf16* op = ctx + (long long)(wq0 + rbase + r) * (H * VH) + h * VH + l15;
#pragma unroll
    for (int nt = 0; nt < 8; nt++) op[nt * 16] = __float2bfloat16(acc[nt][r] * inv);
  }
}

// ---------------------------------------------------------------------------
extern "C" void kernel_launch(void* const* d_in, const int* in_sizes, int n_in,
                              void* d_out, int out_size, void* d_ws, size_t ws_size,
                              hipStream_t stream)
{
  const float* h2     = (const float*)d_in[0];
  const float* cosp   = (const float*)d_in[1];
  const float* sinp   = (const float*)d_in[2];
  const float* w_q_a  = (const float*)d_in[3];
  const float* g_q_a  = (const float*)d_in[4];
  const float* w_q_b  = (const float*)d_in[5];
  const float* w_kv_a = (const float*)d_in[6];
  const float* g_kv_a = (const float*)d_in[7];
  const float* w_uk_t = (const float*)d_in[8];
  const float* w_uv   = (const float*)d_in[9];
  const float* w_o    = (const float*)d_in[10];
  float* out = (float*)d_out;

  // ---- workspace layout (R12 base; q_raw/out_p1 deleted; audited) ----
  // Order: qkv(z=4)->qkv_p | rmsnorm+kvpost consume qkv_p | wo_b cast over
  // qkv_p z0/z1 | q_b writes q2 over qkv_p z2/z3 (dead) | absorb writes k2
  // over wqb_b+q_a_bf (dead after q_b) | attn writes ctx (X tail, qkv_p dead).
  char* ws = (char*)d_ws;
  bf16* wukb   = (bf16*)(ws);                          // 4,194,304  [H][NOPE][KVL]
  bf16* wuv_t  = (bf16*)(ws + 4194304);                // 4,194,304  [H][VH][KVL] (contiguous)
  bf16* kv_cat = (bf16*)(ws + 8388608);                // 2,359,296
  char* X = ws + 13107200;                             // 75,497,472
  char* Y = X + 75497472;                              // 67,108,864
  float* qkv_p = (float*)(X);                          // [4][2048][2112] f32 69,206,016
  bf16*  wo_b  = (bf16*)(X);                           // 33,554,432 (after rmsnorm+kvpost)
  bf16*  q2    = (bf16*)(X + 33554432);                // 25,165,824 (after rmsnorm+kvpost)
  bf16*  ctx   = (bf16*)(X + 58720256);                // 16,777,216 (after attn inputs built)
  bf16*  hb     = (bf16*)(Y);                          // 16,777,216 (dead after qkv GEMM)
  bf16*  wcat_b = (bf16*)(Y + 16777216);               // 17,301,504 (dead after qkv)
  bf16*  wqb_b  = (bf16*)(Y);                          // 18,874,368 (cast after qkv, over hb)
  bf16*  q_a_bf = (bf16*)(Y + 18874368);               // 6,291,456 (dead after q_b)
  bf16*  k2     = (bf16*)(Y);                          // 25,165,824 (absorb, after q_b)
  bf16*  kv_vT  = (bf16*)(Y + 50331648);               // 16,777,216

  // ---- early casts ----
  cast_kernel<<<1024, 256, 0, stream>>>(h2,     hb,     (long long)S * D / 4);
  cast_kernel<<<1024, 256, 0, stream>>>(w_q_a,  wcat_b, (long long)QL * D / 4);
  cast_kernel<<<1024, 256, 0, stream>>>(w_kv_a, wcat_b + (long long)QL * D, (long long)CAT * D / 4);
  cast_kernel<<<1024, 256, 0, stream>>>(w_uk_t, wukb,   (long long)H * NOPE * KVL / 4);
  tcast_kernel<<<dim3(VH / 32, KVL / 32, H), 256, 0, stream>>>(w_uv, wuv_t, KVL, VH);

  // 1+4 merged: qkv partials = hb @ wcat_b^T, mgemm3 256² K-split z=4 (verified)
  mgemm3<float><<<dim3(9, 8, 4), 512, 0, stream>>>(
      hb, wcat_b, qkv_p, qkv_p, S, NCAT, D / 4, D, D, NCAT,
      (long long)(D / 4), (long long)(D / 4), (long long)S * NCAT);
  // cast w_q_b (hb dead; region reused)
  cast_kernel<<<1024, 256, 0, stream>>>(w_q_b, wqb_b, (long long)H * QKH * QL / 4);
  // 2. rmsnorm over 4-partial sum -> q_a_bf
  rmsnorm_cast_kernel<<<dim3(S), 256, 0, stream>>>(
      qkv_p, g_q_a, q_a_bf, NCAT, (long long)S * NCAT);
  // 5. kv post over 4-partial sum -> kv_cat  (BEFORE q_b: q2 overwrites z2/z3)
  kvpost_kernel<<<dim3(S), 256, 0, stream>>>(
      qkv_p + QL, g_kv_a, cosp, sinp, kv_cat, NCAT, (long long)S * NCAT);
  // cast w_o (qkv_p z0/z1 dead)
  cast_kernel<<<1024, 256, 0, stream>>>(w_o, wo_b, (long long)D * H * VH / 4);
  // 3+6 fused: q2 = rope-epilogue(q_a @ w_q_b^T)  (mgemm4 EPI=2, grid 48x8;
  //   qprep + q_raw round-trip eliminated; rope applied on f32 accumulators)
  mgemm4<bf16, 2><<<dim3(H * QKH / 128, S / 256, 1), 512, 0, stream>>>(
      q_a_bf, wqb_b, q2, cosp, sinp, S, H * QKH, QL, QL, QL, CAT2);
  // 5b+7 merged ABSORB: [k_nope_all | v_all] = kv_c @ [wukb; wuv_t]^T (verified)
  mgemm3<bf16, 1><<<dim3(H * (NOPE + VH) / 256, S / 256, 1), 512, 0, stream>>>(
      kv_cat, (const bf16*)ws, k2, kv_vT, S, H * (NOPE + VH), KVL,
      CAT, KVL, 0, 0, 0, 0);
  // 7b. k rope broadcast -> k2[h][...,128:192]
  krope_bcast<<<dim3(S), 256, 0, stream>>>(kv_cat, k2);
  // 8. attention (verified v13) -> ctx bf16 [s][h*128+v]
  attn_mfma13<<<dim3(512), dim3(512), 0, stream>>>(q2, k2, kv_vT, ctx);
  // 10. out = ctx @ w_o^T -> f32  (mgemm4 256x128: 256 tiles = 1/CU, full K,
  //     no K-split, no add pass)
  mgemm4<float><<<dim3(D / 128, S / 256, 1), 512, 0, stream>>>(
      ctx, wo_b, out, nullptr, nullptr, S, D, D, D, D, D);

  (void)in_sizes; (void)n_in; (void)out_size; (void)ws_size;
}

// Round 14
// 394.936 us; speedup vs baseline: 1.0431x; 1.0431x over previous
//
#include <hip/hip_runtime.h>
#include <hip/hip_bf16.h>

typedef __hip_bfloat16 bf16;
typedef __attribute__((ext_vector_type(8))) short  s16x8;  // 8 bf16 = 4 VGPR (MFMA A/B frag)
typedef __attribute__((ext_vector_type(4))) float  f32x4;  // MFMA C/D frag

static constexpr int S    = 2048;
static constexpr int D    = 4096;
static constexpr int H    = 32;
static constexpr int QL   = 1536;
static constexpr int KVL  = 512;
static constexpr int NOPE = 128;
static constexpr int ROPE = 64;
static constexpr int QKH  = 192;
static constexpr int VH   = 128;
static constexpr int CAT  = 576;
static constexpr int CAT2 = 192;    // absorbed head dim: 128 nope + 64 rope
static constexpr int NCAT = 2112;   // QL + CAT (merged q_a/kv_a GEMM width)
static constexpr float EPS = 1e-6f;

__device__ __forceinline__ void stf(float* p, float v){ *p = v; }
__device__ __forceinline__ void stf(bf16* p, float v){ *p = __float2bfloat16(v); }

__device__ __forceinline__ float wave_sum(float v){
#pragma unroll
  for (int off = 32; off; off >>= 1) v += __shfl_xor(v, off, 64);
  return v;
}

__device__ __forceinline__ void gload16(const bf16* src, unsigned short* dst){
  __builtin_amdgcn_global_load_lds(
      (const __attribute__((address_space(1))) unsigned int*)src,
      (__attribute__((address_space(3))) unsigned int*)dst, 16, 0, 0);
}

// ---------------------------------------------------------------------------
// f32 -> bf16 cast, vectorized
// ---------------------------------------------------------------------------
__global__ __launch_bounds__(256)
void cast_kernel(const float* __restrict__ in, bf16* __restrict__ out, long long n4)
{
  long long i = (long long)blockIdx.x * 256 + threadIdx.x;
  const long long stride = (long long)gridDim.x * 256;
  for (; i < n4; i += stride) {
    float4 v = ((const float4*)in)[i];
    union { bf16 b[4]; uint2 u; } t;
    t.b[0] = __float2bfloat16(v.x); t.b[1] = __float2bfloat16(v.y);
    t.b[2] = __float2bfloat16(v.z); t.b[3] = __float2bfloat16(v.w);
    *(uint2*)(out + i * 4) = t.u;
  }
}

// ---------------------------------------------------------------------------
// f32 add: dst += src (K-split combine for the out GEMM)
// ---------------------------------------------------------------------------
__global__ __launch_bounds__(256)
void add_kernel(float* __restrict__ dst, const float* __restrict__ src, long long n4)
{
  long long i = (long long)blockIdx.x * 256 + threadIdx.x;
  const long long stride = (long long)gridDim.x * 256;
  for (; i < n4; i += stride) {
    float4 a = ((const float4*)dst)[i];
    const float4 b = ((const float4*)src)[i];
    a.x += b.x; a.y += b.y; a.z += b.z; a.w += b.w;
    ((float4*)dst)[i] = a;
  }
}

// ---------------------------------------------------------------------------
// transpose-cast: in f32 [batch][R][C] -> out bf16 [batch][C][R]. 32x32 tiles.
// ---------------------------------------------------------------------------
__global__ __launch_bounds__(256)
void tcast_kernel(const float* __restrict__ in, bf16* __restrict__ out, int R, int C)
{
  const long long b = blockIdx.z;
  in  += b * (long long)R * C;
  out += b * (long long)R * C;
  const int c0 = blockIdx.x * 32, r0 = blockIdx.y * 32;
  __shared__ float t[32][33];
  const int tx = threadIdx.x & 31, ty = threadIdx.x >> 5;
#pragma unroll
  for (int p = 0; p < 4; p++)
    t[ty + p * 8][tx] = in[(long long)(r0 + ty + p * 8) * C + c0 + tx];
  __syncthreads();
#pragma unroll
  for (int p = 0; p < 4; p++)
    out[(long long)(c0 + ty + p * 8) * R + r0 + tx] = __float2bfloat16(t[tx][ty + p * 8]);
}

// ---------------------------------------------------------------------------
// MFMA GEMM v3 (verified R10-R13): 256x256 tile, BK=64, 8 waves, counted-vmcnt
// deep pipeline.  Raw s_barrier + s_waitcnt vmcnt(8) keeps the NEXT tile's 8
// global_load_lds in flight ACROSS the barrier.
// EPI=0: C[row*ldc+col] (col<N guarded).
// EPI=1: ABSORB (verified R11): col<4096 -> k2[h][row][col&127] (via C),
//        col>=4096 -> kv_vT[(col-4096)*S + row] (via C2).
// EPI=2: q2 ROPE epilogue (math verified R13): N=6144=H*192; each wave's
//        64-col block lies wholly in one head and is wholly nope or rope;
//        rope pair (r, r^32) = acc[mt][nt] / acc[mt][nt^2] in-register.
//        Writes q2[h][row][192] directly (replaces qprep + q_raw round-trip).
//   (R13 lesson: do NOT shrink the tile to 256x128 -- halves MFMA-per-sync
//    and the fixed barrier/stage cost dominates: 95 us vs ~50.)
// ---------------------------------------------------------------------------
template<typename TC, int EPI = 0>
__global__ __launch_bounds__(512, 2)
void mgemm3(const bf16* __restrict__ A, const bf16* __restrict__ B, TC* __restrict__ C,
            TC* __restrict__ C2, const float* __restrict__ cosp,
            const float* __restrict__ sinp,
            int M, int N, int K, int lda, int ldb, int ldc,
            long long sA, long long sB, long long sC)
{
  A += (long long)blockIdx.z * sA;
  B += (long long)blockIdx.z * sB;
  C += (long long)blockIdx.z * sC;
  __shared__ unsigned short As[2][256 * 64];   // 2 x 32 KB
  __shared__ unsigned short Bs[2][256 * 64];   // 2 x 32 KB
  const int tid = threadIdx.x;
  const int w = tid >> 6;
  const int lane = tid & 63;
  const int l15 = lane & 15, g = lane >> 4;
  const int wr = w >> 2, wc = w & 3;
  const int m0 = blockIdx.y * 256, n0 = blockIdx.x * 256;

  const bf16* asrc[4];
  const bf16* bsrc[4];
#pragma unroll
  for (int j = 0; j < 4; j++) {
    const int f = j * 512 + tid;
    const int row = f >> 3;                 // 0..255
    const int cg = ((f & 7) ^ (row & 7)) * 8;
    asrc[j] = A + (long long)(m0 + row) * lda + cg;
    int br = n0 + row; if (br >= N) br = N - 1;
    bsrc[j] = B + (long long)br * ldb + cg;
  }

  auto stage = [&](int b, int k0) {
#pragma unroll
    for (int j = 0; j < 4; j++) {
      gload16(asrc[j] + k0, &As[b][(j * 512 + w * 64) * 8]);
      gload16(bsrc[j] + k0, &Bs[b][(j * 512 + w * 64) * 8]);
    }
  };

  f32x4 acc[8][4];
#pragma unroll
  for (int i = 0; i < 8; i++)
#pragma unroll
    for (int j = 0; j < 4; j++) acc[i][j] = (f32x4){0.f, 0.f, 0.f, 0.f};

  const int ntk = K >> 6;
  stage(0, 0);

  for (int t = 0; t < ntk; ++t) {
    const int b = t & 1;
    asm volatile("" ::: "memory");
    __builtin_amdgcn_s_barrier();
    if (t + 1 < ntk) {
      stage(b ^ 1, (t + 1) << 6);
      asm volatile("s_waitcnt vmcnt(8)" ::: "memory");
    } else {
      asm volatile("s_waitcnt vmcnt(0)" ::: "memory");
    }
    __builtin_amdgcn_s_barrier();
    asm volatile("" ::: "memory");

    const unsigned short* Ab = &As[b][(wr * 128 + l15) * 64];
    const unsigned short* Bb = &Bs[b][(wc * 64 + l15) * 64];
    const int swz = l15 & 7;
#pragma unroll
    for (int kk = 0; kk < 2; ++kk) {
      const int co = (((kk * 4 + g) ^ swz) * 8);
      s16x8 a[8], bb[4];
#pragma unroll
      for (int mt = 0; mt < 8; mt++)
        a[mt] = *(const s16x8*)(Ab + mt * 1024 + co);
#pragma unroll
      for (int nt = 0; nt < 4; nt++)
        bb[nt] = *(const s16x8*)(Bb + nt * 1024 + co);
      __builtin_amdgcn_s_setprio(1);
#pragma unroll
      for (int mt = 0; mt < 8; mt++)
#pragma unroll
        for (int nt = 0; nt < 4; nt++)
          acc[mt][nt] = __builtin_amdgcn_mfma_f32_16x16x32_bf16(a[mt], bb[nt], acc[mt][nt], 0, 0, 0);
      __builtin_amdgcn_s_setprio(0);
    }
  }

  if constexpr (EPI == 2) {
    // ROPE epilogue: wave's 64-col block = blk; head hh = blk/3; dbase {0,64,128}
    const int blk = blockIdx.x * 4 + wc;
    const int hh = blk / 3;
    const int dbase = (blk % 3) * 64;
    const bool isrope = (dbase == 128);
#pragma unroll
    for (int mt = 0; mt < 8; mt++) {
      const int row0 = m0 + wr * 128 + mt * 16 + g * 4;
#pragma unroll
      for (int nt = 0; nt < 4; nt++) {
        if (!isrope) {
          const int d = dbase + nt * 16 + l15;
#pragma unroll
          for (int r = 0; r < 4; r++)
            stf((bf16*)C + ((long long)hh * S + row0 + r) * CAT2 + d, acc[mt][nt][r]);
        } else {
          const int rr = nt * 16 + l15;     // rope dim 0..63
#pragma unroll
          for (int r = 0; r < 4; r++) {
            const int srow = row0 + r;
            const float x   = acc[mt][nt][r];
            const float xp  = acc[mt][nt ^ 2][r];     // col +/- 32, in-register
            const float rot = (rr < 32) ? -xp : xp;
            stf((bf16*)C + ((long long)hh * S + srow) * CAT2 + NOPE + rr,
                x * cosp[srow * ROPE + rr] + rot * sinp[srow * ROPE + rr]);
          }
        }
      }
    }
  } else {
#pragma unroll
    for (int mt = 0; mt < 8; mt++)
#pragma unroll
      for (int nt = 0; nt < 4; nt++) {
        const int col = n0 + wc * 64 + nt * 16 + l15;
        const int row0 = m0 + wr * 128 + mt * 16 + g * 4;
        if constexpr (EPI == 0) {
          if (col < N) {
#pragma unroll
            for (int r = 0; r < 4; r++)
              stf(C + (long long)(row0 + r) * ldc + col, acc[mt][nt][r]);
          }
        } else {
          if (col < H * NOPE) {               // key-absorb -> k2[h][row][n]
            TC* dst = C + ((long long)(col >> 7) * S + row0) * CAT2 + (col & 127);
#pragma unroll
            for (int r = 0; r < 4; r++)
              stf(dst + (long long)r * CAT2, acc[mt][nt][r]);
          } else {                             // value-absorb -> kv_vT[c'][row]
            TC* dst = C2 + (long long)(col - H * NOPE) * S + row0;
#pragma unroll
            for (int r = 0; r < 4; r++)
              stf(dst + r, acc[mt][nt][r]);
          }
        }
      }
  }
}

// ---------------------------------------------------------------------------
// RMSNorm over SUM of FOUR K-split partials (z-stride poff), N = QL fixed.
// ---------------------------------------------------------------------------
__global__ __launch_bounds__(256)
void rmsnorm_cast_kernel(const float* __restrict__ x, const float* __restrict__ g,
                         bf16* __restrict__ out, int ldx, long long poff)
{
  const int row = blockIdx.x;
  const float* xr = x + (long long)row * ldx;
  float v[6];
  float ss = 0.f;
#pragma unroll
  for (int k = 0; k < 6; k++) {
    const int c = threadIdx.x + (k << 8);
    const float t = xr[c] + xr[c + poff] + xr[c + 2 * poff] + xr[c + 3 * poff];
    v[k] = t; ss += t * t;
  }
  __shared__ float red[4];
  ss = wave_sum(ss);
  if ((threadIdx.x & 63) == 0) red[threadIdx.x >> 6] = ss;
  __syncthreads();
  const float inv = rsqrtf((red[0] + red[1] + red[2] + red[3]) / (float)QL + EPS);
#pragma unroll
  for (int k = 0; k < 6; k++) {
    const int c = threadIdx.x + (k << 8);
    out[(long long)row * QL + c] = __float2bfloat16(v[k] * inv * g[c]);
  }
}

// ---------------------------------------------------------------------------
// kv post over SUM of FOUR K-split partials (row stride ldr, z-stride poff).
// ---------------------------------------------------------------------------
__global__ __launch_bounds__(256)
void kvpost_kernel(const float* __restrict__ kv_raw, const float* __restrict__ g,
                   const float* __restrict__ cosp, const float* __restrict__ sinp,
                   bf16* __restrict__ kv_cat, int ldr, long long poff)
{
  const int s = blockIdx.x;
  const float* row = kv_raw + (long long)s * ldr;
  float v[2];
  float ss = 0.f;
#pragma unroll
  for (int k = 0; k < 2; k++) {
    const int c = threadIdx.x + (k << 8);
    const float t = row[c] + row[c + poff] + row[c + 2 * poff] + row[c + 3 * poff];
    v[k] = t; ss += t * t;
  }
  __shared__ float red[4];
  float ws_ = wave_sum(ss);
  if ((threadIdx.x & 63) == 0) red[threadIdx.x >> 6] = ws_;
  __syncthreads();
  const float inv = rsqrtf((red[0] + red[1] + red[2] + red[3]) / (float)KVL + EPS);
#pragma unroll
  for (int k = 0; k < 2; k++) {
    const int c = threadIdx.x + (k << 8);
    kv_cat[(long long)s * CAT + c] = __float2bfloat16(v[k] * inv * g[c]);
  }
  if (threadIdx.x < 64) {
    const int r = threadIdx.x;
    const int c = KVL + r;
    const float x = row[c] + row[c + poff] + row[c + 2 * poff] + row[c + 3 * poff];
    const float xp = __shfl_xor(x, 32, 64);
    const float rot = (r < 32) ? -xp : xp;
    kv_cat[(long long)s * CAT + KVL + r] =
        __float2bfloat16(x * cosp[s * ROPE + r] + rot * sinp[s * ROPE + r]);
  }
}

// ---------------------------------------------------------------------------
// k rope broadcast: k2[h][s][128+r] = kv_cat[s][512+r] for all heads
// ---------------------------------------------------------------------------
__global__ __launch_bounds__(256)
void krope_bcast(const bf16* __restrict__ kv_cat, bf16* __restrict__ k2)
{
  const int s = blockIdx.x;
  const int h = threadIdx.x >> 3;
  const int i = (threadIdx.x & 7) * 8;
  *(uint4*)(k2 + ((long long)h * S + s) * CAT2 + NOPE + i) =
      *(const uint4*)(kv_cat + (long long)s * CAT + KVL + i);
}

// ---------------------------------------------------------------------------
// MFMA flash attention v13 (verified R4-R13, 81 us): key+value absorbed,
// head dim 192, cheap overflow-detect softmax, stage-before-compute +
// single __syncthreads skeleton.
// ---------------------------------------------------------------------------
__global__ __launch_bounds__(512, 2)
void attn_mfma13(const bf16* __restrict__ q2, const bf16* __restrict__ k2,
                 const bf16* __restrict__ kv_vT, bf16* __restrict__ ctx)
{
  __shared__ unsigned short kkl[2][32 * CAT2];  // 2 x 12,288 B  K tiles (swizzled)
  __shared__ unsigned short vtl[2][128 * 32];   // 2 x  8,192 B  V^T tiles (swizzled)
  __shared__ unsigned short ps[8][16][40];      // 10,240 B per-wave P transpose
  const int tid = threadIdx.x;
  const int bid = blockIdx.x;
  const int h  = bid & 31;
  const int qb = 15 - (bid >> 5);               // heavy blocks dispatched first
  const int w = tid >> 6, lane = tid & 63;
  const int l15 = lane & 15, g = lane >> 4;
  const int wq0 = qb * 128 + w * 16;
  const int rbase = g * 4;
  const float scale = 0.07216878364870322f;     // 1/sqrt(192)

  const bf16* ksrc[2];
#pragma unroll
  for (int j = 0; j < 2; j++) {
    const int f  = j * 512 + ((j == 1) ? (tid & 255) : tid);
    const int r  = f / 24;
    const int cg = ((f % 24) << 4) ^ ((r & 7) << 4);
    ksrc[j] = k2 + ((long long)h * S + r) * CAT2 + (cg >> 1);
  }
  const int vc = tid >> 2;
  const bf16* vsrc = kv_vT + (long long)h * VH * S + (long long)vc * S
                   + (((tid & 3) ^ ((vc >> 1) & 3)) * 8);

  auto stage = [&](int buf, int kbase) {
    gload16(ksrc[0] + (long long)kbase * CAT2, &kkl[buf][(w * 64) * 8]);
    if (tid < 256)
      gload16(ksrc[1] + (long long)kbase * CAT2, &kkl[buf][(512 + w * 64) * 8]);
    gload16(vsrc + kbase, &vtl[buf][(w * 64) * 8]);
  };

  s16x8 qf[6];
  const bf16* qp = q2 + ((long long)h * S + (wq0 + l15)) * CAT2 + g * 8;
#pragma unroll
  for (int ch = 0; ch < 6; ch++) qf[ch] = *(const s16x8*)(qp + ch * 32);

  s16x8 ones;
#pragma unroll
  for (int i = 0; i < 8; i++) ones[i] = (short)0x3F80;

  f32x4 acc[8];
#pragma unroll
  for (int nt = 0; nt < 8; nt++) acc[nt] = (f32x4){0.f, 0.f, 0.f, 0.f};
  f32x4 accl = (f32x4){0.f, 0.f, 0.f, 0.f};
  float mrow[4];
#pragma unroll
  for (int r = 0; r < 4; r++) mrow[r] = -3e38f;

  stage(0, 0);
  __syncthreads();

  const int ntb = 4 * qb + 4;
  int buf = 0;
  for (int t = 0; t < ntb; t++) {
    const int kbase = t * 32;
    if (t + 1 < ntb) stage(buf ^ 1, kbase + 32);   // overlap with compute(t)
    if (kbase <= wq0 + 15) {
      f32x4 st0 = (f32x4){0.f,0.f,0.f,0.f}, st1 = (f32x4){0.f,0.f,0.f,0.f};
      const unsigned short* kb0 = &kkl[buf][l15 * CAT2];
      const int rsw = (l15 & 7) << 4;
#pragma unroll
      for (int ch = 0; ch < 6; ch++) {
        const int cb = ((ch * 64 + g * 16) ^ rsw) >> 1;
        s16x8 b0 = *(const s16x8*)(kb0 + cb);
        s16x8 b1 = *(const s16x8*)(kb0 + 16 * CAT2 + cb);
        st0 = __builtin_amdgcn_mfma_f32_16x16x32_bf16(qf[ch], b0, st0, 0, 0, 0);
        st1 = __builtin_amdgcn_mfma_f32_16x16x32_bf16(qf[ch], b1, st1, 0, 0, 0);
      }
      float p0v[4], p1v[4];
      float pmax = 0.f;
#pragma unroll
      for (int r = 0; r < 4; r++) {
        const int qg = wq0 + rbase + r;
        const bool v0 = (kbase + l15) <= qg, v1 = (kbase + 16 + l15) <= qg;
        const float s0 = st0[r] * scale, s1 = st1[r] * scale;
        const float p0 = v0 ? __expf(s0 - mrow[r]) : 0.f;
        const float p1 = v1 ? __expf(s1 - mrow[r]) : 0.f;
        p0v[r] = p0; p1v[r] = p1;
        pmax = fmaxf(pmax, fmaxf(p0, p1));
      }
      if (__builtin_expect(__any(pmax > 2981.0f), 0)) {   // rare: growth > ~8
#pragma unroll
        for (int r = 0; r < 4; r++) {
          const int qg = wq0 + rbase + r;
          const bool v0 = (kbase + l15) <= qg, v1 = (kbase + 16 + l15) <= qg;
          const float s0 = st0[r] * scale, s1 = st1[r] * scale;
          float tmax = fmaxf(v0 ? s0 : -3e38f, v1 ? s1 : -3e38f);
#pragma unroll
          for (int off = 8; off; off >>= 1) tmax = fmaxf(tmax, __shfl_xor(tmax, off, 64));
          if (tmax > mrow[r] + 8.0f) {
            const float corr = __expf(mrow[r] - tmax);    // 0 on first tile
            mrow[r] = tmax;
#pragma unroll
            for (int nt = 0; nt < 8; nt++) acc[nt][r] *= corr;
            accl[r] *= corr;
            p0v[r] = v0 ? __expf(s0 - mrow[r]) : 0.f;
            p1v[r] = v1 ? __expf(s1 - mrow[r]) : 0.f;
          }
        }
      }
#pragma unroll
      for (int r = 0; r < 4; r++) {
        union { bf16 b; unsigned short u; } c0, c1;
        c0.b = __float2bfloat16(p0v[r]); c1.b = __float2bfloat16(p1v[r]);
        ps[w][rbase + r][l15]      = c0.u;
        ps[w][rbase + r][16 + l15] = c1.u;
      }
      asm volatile("" ::: "memory");   // order ps stores before reads (per-wave)
      s16x8 pa = *(const s16x8*)&ps[w][l15][g * 8];
      const unsigned short* vt = &vtl[buf][l15 * 32 + ((g * 8) ^ (((l15 >> 1) & 3) * 8))];
#pragma unroll
      for (int nt = 0; nt < 8; nt++) {
        s16x8 bv = *(const s16x8*)(vt + nt * 512);
        acc[nt] = __builtin_amdgcn_mfma_f32_16x16x32_bf16(pa, bv, acc[nt], 0, 0, 0);
      }
      accl = __builtin_amdgcn_mfma_f32_16x16x32_bf16(pa, ones, accl, 0, 0, 0);
    }
    __syncthreads();   // drains stage(t+1) loads + all waves done with buf
    buf ^= 1;
  }

#pragma unroll
  for (int r = 0; r < 4; r++) {
    const float inv = 1.f / accl[r];
    bf16* op = ctx + (long long)(wq0 + rbase + r) * (H * VH) + h * VH + l15;
#pragma unroll
    for (int nt = 0; nt < 8; nt++) op[nt * 16] = __float2bfloat16(acc[nt][r] * inv);
  }
}

// ---------------------------------------------------------------------------
extern "C" void kernel_launch(void* const* d_in, const int* in_sizes, int n_in,
                              void* d_out, int out_size, void* d_ws, size_t ws_size,
                              hipStream_t stream)
{
  const float* h2     = (const float*)d_in[0];
  const float* cosp   = (const float*)d_in[1];
  const float* sinp   = (const float*)d_in[2];
  const float* w_q_a  = (const float*)d_in[3];
  const float* g_q_a  = (const float*)d_in[4];
  const float* w_q_b  = (const float*)d_in[5];
  const float* w_kv_a = (const float*)d_in[6];
  const float* g_kv_a = (const float*)d_in[7];
  const float* w_uk_t = (const float*)d_in[8];
  const float* w_uv   = (const float*)d_in[9];
  const float* w_o    = (const float*)d_in[10];
  float* out = (float*)d_out;

  // ---- workspace layout (R13 base + out_p1 restored over dead k2) ----
  char* ws = (char*)d_ws;
  bf16* wukb   = (bf16*)(ws);                          // 4,194,304  [H][NOPE][KVL]
  bf16* wuv_t  = (bf16*)(ws + 4194304);                // 4,194,304  [H][VH][KVL] (contiguous)
  bf16* kv_cat = (bf16*)(ws + 8388608);                // 2,359,296
  char* X = ws + 13107200;                             // 75,497,472
  char* Y = X + 75497472;                              // 67,108,864
  float* qkv_p = (float*)(X);                          // [4][2048][2112] f32 69,206,016
  bf16*  wo_b  = (bf16*)(X);                           // 33,554,432 (after rmsnorm+kvpost)
  bf16*  q2    = (bf16*)(X + 33554432);                // 25,165,824 (after rmsnorm+kvpost)
  bf16*  ctx   = (bf16*)(X + 58720256);                // 16,777,216 (attn output)
  bf16*  hb     = (bf16*)(Y);                          // 16,777,216 (dead after qkv GEMM)
  bf16*  wcat_b = (bf16*)(Y + 16777216);               // 17,301,504 (dead after qkv)
  bf16*  wqb_b  = (bf16*)(Y);                          // 18,874,368 (cast after qkv, over hb)
  bf16*  q_a_bf = (bf16*)(Y + 18874368);               // 6,291,456 (dead after q_b)
  bf16*  k2     = (bf16*)(Y);                          // 25,165,824 (absorb, after q_b)
  bf16*  kv_vT  = (bf16*)(Y + 50331648);               // 16,777,216
  float* out_p1 = (float*)(Y);                         // 33,554,432 (after attn; k2 dead)

  // ---- early casts ----
  cast_kernel<<<1024, 256, 0, stream>>>(h2,     hb,     (long long)S * D / 4);
  cast_kernel<<<1024, 256, 0, stream>>>(w_q_a,  wcat_b, (long long)QL * D / 4);
  cast_kernel<<<1024, 256, 0, stream>>>(w_kv_a, wcat_b + (long long)QL * D, (long long)CAT * D / 4);
  cast_kernel<<<1024, 256, 0, stream>>>(w_uk_t, wukb,   (long long)H * NOPE * KVL / 4);
  tcast_kernel<<<dim3(VH / 32, KVL / 32, H), 256, 0, stream>>>(w_uv, wuv_t, KVL, VH);

  // 1+4 merged: qkv partials = hb @ wcat_b^T, mgemm3 256² K-split z=4 (verified)
  mgemm3<float><<<dim3(9, 8, 4), 512, 0, stream>>>(
      hb, wcat_b, qkv_p, qkv_p, nullptr, nullptr, S, NCAT, D / 4, D, D, NCAT,
      (long long)(D / 4), (long long)(D / 4), (long long)S * NCAT);
  // cast w_q_b (hb dead; region reused)
  cast_kernel<<<1024, 256, 0, stream>>>(w_q_b, wqb_b, (long long)H * QKH * QL / 4);
  // 2. rmsnorm over 4-partial sum -> q_a_bf
  rmsnorm_cast_kernel<<<dim3(S), 256, 0, stream>>>(
      qkv_p, g_q_a, q_a_bf, NCAT, (long long)S * NCAT);
  // 5. kv post over 4-partial sum -> kv_cat  (BEFORE q_b: q2 overwrites z2/z3)
  kvpost_kernel<<<dim3(S), 256, 0, stream>>>(
      qkv_p + QL, g_kv_a, cosp, sinp, kv_cat, NCAT, (long long)S * NCAT);
  // cast w_o (qkv_p z0/z1 dead)
  cast_kernel<<<1024, 256, 0, stream>>>(w_o, wo_b, (long long)D * H * VH / 4);
  // 3+6 fused: q2 = rope-epilogue(q_a @ w_q_b^T)  (mgemm3 EPI=2, 256² tile,
  //   grid 24x8 = 192 blocks — the R12-verified q_b shape + fused rope)
  mgemm3<bf16, 2><<<dim3(H * QKH / 256, S / 256, 1), 512, 0, stream>>>(
      q_a_bf, wqb_b, q2, q2, cosp, sinp, S, H * QKH, QL, QL, QL, CAT2, 0, 0, 0);
  // 5b+7 merged ABSORB: [k_nope_all | v_all] = kv_c @ [wukb; wuv_t]^T (verified)
  mgemm3<bf16, 1><<<dim3(H * (NOPE + VH) / 256, S / 256, 1), 512, 0, stream>>>(
      kv_cat, (const bf16*)ws, k2, kv_vT, nullptr, nullptr,
      S, H * (NOPE + VH), KVL, CAT, KVL, 0, 0, 0, 0);
  // 7b. k rope broadcast -> k2[h][...,128:192]
  krope_bcast<<<dim3(S), 256, 0, stream>>>(kv_cat, k2);
  // 8. attention (verified v13) -> ctx bf16 [s][h*128+v]
  attn_mfma13<<<dim3(512), dim3(512), 0, stream>>>(q2, k2, kv_vT, ctx);
  // 10. out = ctx @ w_o^T -> f32, mgemm3 256² K-split z=2 (R12-verified)
  const long long ooff = (long long)(out_p1 - out);
  mgemm3<float><<<dim3(16, 8, 2), 512, 0, stream>>>(
      ctx, wo_b, out, out, nullptr, nullptr, S, D, D / 2, D, D, D,
      (long long)(D / 2), (long long)(D / 2), ooff);
  // 10b. combine: out += out_p1
  add_kernel<<<1024, 256, 0, stream>>>(out, out_p1, (long long)S * D / 4);

  (void)in_sizes; (void)n_in; (void)out_size; (void)ws_size;
}

// Round 15
// 385.369 us; speedup vs baseline: 1.0690x; 1.0248x over previous
//
#include <hip/hip_runtime.h>
#include <hip/hip_bf16.h>

typedef __hip_bfloat16 bf16;
typedef __attribute__((ext_vector_type(8))) short  s16x8;  // 8 bf16 = 4 VGPR (MFMA A/B frag)
typedef __attribute__((ext_vector_type(4))) float  f32x4;  // MFMA C/D frag

static constexpr int S    = 2048;
static constexpr int D    = 4096;
static constexpr int H    = 32;
static constexpr int QL   = 1536;
static constexpr int KVL  = 512;
static constexpr int NOPE = 128;
static constexpr int ROPE = 64;
static constexpr int QKH  = 192;
static constexpr int VH   = 128;
static constexpr int CAT  = 576;
static constexpr int CAT2 = 192;    // absorbed head dim: 128 nope + 64 rope
static constexpr int NCAT = 2112;   // QL + CAT (merged q_a/kv_a GEMM width)
static constexpr float EPS = 1e-6f;

__device__ __forceinline__ void stf(float* p, float v){ *p = v; }
__device__ __forceinline__ void stf(bf16* p, float v){ *p = __float2bfloat16(v); }

__device__ __forceinline__ float wave_sum(float v){
#pragma unroll
  for (int off = 32; off; off >>= 1) v += __shfl_xor(v, off, 64);
  return v;
}

__device__ __forceinline__ void gload16(const bf16* src, unsigned short* dst){
  __builtin_amdgcn_global_load_lds(
      (const __attribute__((address_space(1))) unsigned int*)src,
      (__attribute__((address_space(3))) unsigned int*)dst, 16, 0, 0);
}

// ---------------------------------------------------------------------------
// f32 -> bf16 cast, vectorized
// ---------------------------------------------------------------------------
__global__ __launch_bounds__(256)
void cast_kernel(const float* __restrict__ in, bf16* __restrict__ out, long long n4)
{
  long long i = (long long)blockIdx.x * 256 + threadIdx.x;
  const long long stride = (long long)gridDim.x * 256;
  for (; i < n4; i += stride) {
    float4 v = ((const float4*)in)[i];
    union { bf16 b[4]; uint2 u; } t;
    t.b[0] = __float2bfloat16(v.x); t.b[1] = __float2bfloat16(v.y);
    t.b[2] = __float2bfloat16(v.z); t.b[3] = __float2bfloat16(v.w);
    *(uint2*)(out + i * 4) = t.u;
  }
}

// ---------------------------------------------------------------------------
// f32 add: dst += src (K-split combine for the out GEMM)
// ---------------------------------------------------------------------------
__global__ __launch_bounds__(256)
void add_kernel(float* __restrict__ dst, const float* __restrict__ src, long long n4)
{
  long long i = (long long)blockIdx.x * 256 + threadIdx.x;
  const long long stride = (long long)gridDim.x * 256;
  for (; i < n4; i += stride) {
    float4 a = ((const float4*)dst)[i];
    const float4 b = ((const float4*)src)[i];
    a.x += b.x; a.y += b.y; a.z += b.z; a.w += b.w;
    ((float4*)dst)[i] = a;
  }
}

// ---------------------------------------------------------------------------
// transpose-cast: in f32 [batch][R][C] -> out bf16 [batch][C][R]. 32x32 tiles.
// ---------------------------------------------------------------------------
__global__ __launch_bounds__(256)
void tcast_kernel(const float* __restrict__ in, bf16* __restrict__ out, int R, int C)
{
  const long long b = blockIdx.z;
  in  += b * (long long)R * C;
  out += b * (long long)R * C;
  const int c0 = blockIdx.x * 32, r0 = blockIdx.y * 32;
  __shared__ float t[32][33];
  const int tx = threadIdx.x & 31, ty = threadIdx.x >> 5;
#pragma unroll
  for (int p = 0; p < 4; p++)
    t[ty + p * 8][tx] = in[(long long)(r0 + ty + p * 8) * C + c0 + tx];
  __syncthreads();
#pragma unroll
  for (int p = 0; p < 4; p++)
    out[(long long)(c0 + ty + p * 8) * R + r0 + tx] = __float2bfloat16(t[tx][ty + p * 8]);
}

// ---------------------------------------------------------------------------
// mgemm3 CORE (verified R10-R14 body, extracted as a device function so the
// fused dispatch can run multiple independent GEMMs concurrently):
// 256x256 tile, BK=64, 8 waves, counted-vmcnt deep pipeline.
// EPI=0: C[row*ldc+col] (col<N guarded).
// EPI=1: ABSORB (verified R11): col<4096 -> k2[h][row][col&127] (via C),
//        col>=4096 -> kv_vT[(col-4096)*S + row] (via C2).
// EPI=2: q2 ROPE epilogue (verified R14): 64-col block wholly one head,
//        wholly nope or rope; pair (r, r^32) = acc[mt][nt]/acc[mt][nt^2].
// ---------------------------------------------------------------------------
template<typename TC, int EPI>
__device__ __forceinline__ void mg3_core(
    unsigned short (*As)[256 * 64], unsigned short (*Bs)[256 * 64],
    const bf16* __restrict__ A, const bf16* __restrict__ B,
    TC* __restrict__ C, TC* __restrict__ C2,
    const float* __restrict__ cosp, const float* __restrict__ sinp,
    int N, int K, int lda, int ldb, int ldc, int bx, int by)
{
  const int tid = threadIdx.x;
  const int w = tid >> 6;
  const int lane = tid & 63;
  const int l15 = lane & 15, g = lane >> 4;
  const int wr = w >> 2, wc = w & 3;
  const int m0 = by * 256, n0 = bx * 256;

  const bf16* asrc[4];
  const bf16* bsrc[4];
#pragma unroll
  for (int j = 0; j < 4; j++) {
    const int f = j * 512 + tid;
    const int row = f >> 3;                 // 0..255
    const int cg = ((f & 7) ^ (row & 7)) * 8;
    asrc[j] = A + (long long)(m0 + row) * lda + cg;
    int br = n0 + row; if (br >= N) br = N - 1;
    bsrc[j] = B + (long long)br * ldb + cg;
  }

  auto stage = [&](int b, int k0) {
#pragma unroll
    for (int j = 0; j < 4; j++) {
      gload16(asrc[j] + k0, &As[b][(j * 512 + w * 64) * 8]);
      gload16(bsrc[j] + k0, &Bs[b][(j * 512 + w * 64) * 8]);
    }
  };

  f32x4 acc[8][4];
#pragma unroll
  for (int i = 0; i < 8; i++)
#pragma unroll
    for (int j = 0; j < 4; j++) acc[i][j] = (f32x4){0.f, 0.f, 0.f, 0.f};

  const int ntk = K >> 6;
  stage(0, 0);

  for (int t = 0; t < ntk; ++t) {
    const int b = t & 1;
    asm volatile("" ::: "memory");
    __builtin_amdgcn_s_barrier();
    if (t + 1 < ntk) {
      stage(b ^ 1, (t + 1) << 6);
      asm volatile("s_waitcnt vmcnt(8)" ::: "memory");
    } else {
      asm volatile("s_waitcnt vmcnt(0)" ::: "memory");
    }
    __builtin_amdgcn_s_barrier();
    asm volatile("" ::: "memory");

    const unsigned short* Ab = &As[b][(wr * 128 + l15) * 64];
    const unsigned short* Bb = &Bs[b][(wc * 64 + l15) * 64];
    const int swz = l15 & 7;
#pragma unroll
    for (int kk = 0; kk < 2; ++kk) {
      const int co = (((kk * 4 + g) ^ swz) * 8);
      s16x8 a[8], bb[4];
#pragma unroll
      for (int mt = 0; mt < 8; mt++)
        a[mt] = *(const s16x8*)(Ab + mt * 1024 + co);
#pragma unroll
      for (int nt = 0; nt < 4; nt++)
        bb[nt] = *(const s16x8*)(Bb + nt * 1024 + co);
      __builtin_amdgcn_s_setprio(1);
#pragma unroll
      for (int mt = 0; mt < 8; mt++)
#pragma unroll
        for (int nt = 0; nt < 4; nt++)
          acc[mt][nt] = __builtin_amdgcn_mfma_f32_16x16x32_bf16(a[mt], bb[nt], acc[mt][nt], 0, 0, 0);
      __builtin_amdgcn_s_setprio(0);
    }
  }

  if constexpr (EPI == 2) {
    const int blk = bx * 4 + wc;
    const int hh = blk / 3;
    const int dbase = (blk % 3) * 64;
    const bool isrope = (dbase == 128);
#pragma unroll
    for (int mt = 0; mt < 8; mt++) {
      const int row0 = m0 + wr * 128 + mt * 16 + g * 4;
#pragma unroll
      for (int nt = 0; nt < 4; nt++) {
        if (!isrope) {
          const int d = dbase + nt * 16 + l15;
#pragma unroll
          for (int r = 0; r < 4; r++)
            stf((bf16*)C + ((long long)hh * S + row0 + r) * CAT2 + d, acc[mt][nt][r]);
        } else {
          const int rr = nt * 16 + l15;     // rope dim 0..63
#pragma unroll
          for (int r = 0; r < 4; r++) {
            const int srow = row0 + r;
            const float x   = acc[mt][nt][r];
            const float xp  = acc[mt][nt ^ 2][r];     // col +/- 32, in-register
            const float rot = (rr < 32) ? -xp : xp;
            stf((bf16*)C + ((long long)hh * S + srow) * CAT2 + NOPE + rr,
                x * cosp[srow * ROPE + rr] + rot * sinp[srow * ROPE + rr]);
          }
        }
      }
    }
  } else {
#pragma unroll
    for (int mt = 0; mt < 8; mt++)
#pragma unroll
      for (int nt = 0; nt < 4; nt++) {
        const int col = n0 + wc * 64 + nt * 16 + l15;
        const int row0 = m0 + wr * 128 + mt * 16 + g * 4;
        if constexpr (EPI == 0) {
          if (col < N) {
#pragma unroll
            for (int r = 0; r < 4; r++)
              stf(C + (long long)(row0 + r) * ldc + col, acc[mt][nt][r]);
          }
        } else {
          if (col < H * NOPE) {               // key-absorb -> k2[h][row][n]
            TC* dst = C + ((long long)(col >> 7) * S + row0) * CAT2 + (col & 127);
#pragma unroll
            for (int r = 0; r < 4; r++)
              stf(dst + (long long)r * CAT2, acc[mt][nt][r]);
          } else {                             // value-absorb -> kv_vT[c'][row]
            TC* dst = C2 + (long long)(col - H * NOPE) * S + row0;
#pragma unroll
            for (int r = 0; r < 4; r++)
              stf(dst + r, acc[mt][nt][r]);
          }
        }
      }
  }
}

// ---------------------------------------------------------------------------
// standalone mgemm3 (qkv, out GEMMs): z-batch/K-split plumbing + core
// ---------------------------------------------------------------------------
template<typename TC, int EPI = 0>
__global__ __launch_bounds__(512, 2)
void mgemm3(const bf16* __restrict__ A, const bf16* __restrict__ B, TC* __restrict__ C,
            TC* __restrict__ C2, const float* __restrict__ cosp,
            const float* __restrict__ sinp,
            int M, int N, int K, int lda, int ldb, int ldc,
            long long sA, long long sB, long long sC)
{
  A += (long long)blockIdx.z * sA;
  B += (long long)blockIdx.z * sB;
  C += (long long)blockIdx.z * sC;
  __shared__ unsigned short As[2][256 * 64];   // 2 x 32 KB
  __shared__ unsigned short Bs[2][256 * 64];   // 2 x 32 KB
  mg3_core<TC, EPI>(As, Bs, A, B, C, C2, cosp, sinp,
                    N, K, lda, ldb, ldc, blockIdx.x, blockIdx.y);
  (void)M;
}

// ---------------------------------------------------------------------------
// FUSED dispatch: q_b(rope) GEMM + ABSORB GEMM + krope broadcast in ONE
// 512-block launch.  All three are independent (q_b: q_a_bf x wqb -> q2;
// absorb: kv_cat x [wukb;wuv_t] -> k2/kv_vT; krope: kv_cat -> k2 rope cols).
// Serial they waste 64 idle CUs during q_b (192 blocks @ 1 block/CU);
// fused, absorb fills those CUs.  Long q_b blocks dispatch first.
// ---------------------------------------------------------------------------
__global__ __launch_bounds__(512, 2)
void fused_qba(const bf16* __restrict__ q_a_bf, const bf16* __restrict__ wqb,
               bf16* __restrict__ q2,
               const bf16* __restrict__ kv_cat, const bf16* __restrict__ wabs,
               bf16* __restrict__ k2, bf16* __restrict__ kv_vT,
               const float* __restrict__ cosp, const float* __restrict__ sinp)
{
  __shared__ unsigned short As[2][256 * 64];
  __shared__ unsigned short Bs[2][256 * 64];
  const int f = blockIdx.x;
  if (f < 192) {                       // q_b + rope epilogue (grid 24x8)
    mg3_core<bf16, 2>(As, Bs, q_a_bf, wqb, q2, q2, cosp, sinp,
                      H * QKH, QL, QL, QL, CAT2, f % 24, f / 24);
  } else if (f < 448) {                // absorb (grid 32x8)
    const int ff = f - 192;
    mg3_core<bf16, 1>(As, Bs, kv_cat, wabs, k2, kv_vT, nullptr, nullptr,
                      H * (NOPE + VH), KVL, CAT, KVL, 0, ff % 32, ff / 32);
  } else {                             // krope: k2[h][s][128..191] = kv_cat[s][512..575]
    const int base = (f - 448) * 512 + threadIdx.x;   // 0..32767
#pragma unroll
    for (int it = 0; it < 16; ++it) {
      const int idx = base + it * 32768;              // 0..524287 (uint4 units)
      const int i8 = idx & 7;
      const int hh = (idx >> 3) & 31;
      const int s  = idx >> 8;
      *(uint4*)(k2 + ((long long)hh * S + s) * CAT2 + NOPE + i8 * 8) =
          *(const uint4*)(kv_cat + (long long)s * CAT + KVL + i8 * 8);
    }
  }
}

// ---------------------------------------------------------------------------
// RMSNorm over SUM of FOUR K-split partials (z-stride poff), N = QL fixed.
// ---------------------------------------------------------------------------
__global__ __launch_bounds__(256)
void rmsnorm_cast_kernel(const float* __restrict__ x, const float* __restrict__ g,
                         bf16* __restrict__ out, int ldx, long long poff)
{
  const int row = blockIdx.x;
  const float* xr = x + (long long)row * ldx;
  float v[6];
  float ss = 0.f;
#pragma unroll
  for (int k = 0; k < 6; k++) {
    const int c = threadIdx.x + (k << 8);
    const float t = xr[c] + xr[c + poff] + xr[c + 2 * poff] + xr[c + 3 * poff];
    v[k] = t; ss += t * t;
  }
  __shared__ float red[4];
  ss = wave_sum(ss);
  if ((threadIdx.x & 63) == 0) red[threadIdx.x >> 6] = ss;
  __syncthreads();
  const float inv = rsqrtf((red[0] + red[1] + red[2] + red[3]) / (float)QL + EPS);
#pragma unroll
  for (int k = 0; k < 6; k++) {
    const int c = threadIdx.x + (k << 8);
    out[(long long)row * QL + c] = __float2bfloat16(v[k] * inv * g[c]);
  }
}

// ---------------------------------------------------------------------------
// kv post over SUM of FOUR K-split partials (row stride ldr, z-stride poff).
// ---------------------------------------------------------------------------
__global__ __launch_bounds__(256)
void kvpost_kernel(const float* __restrict__ kv_raw, const float* __restrict__ g,
                   const float* __restrict__ cosp, const float* __restrict__ sinp,
                   bf16* __restrict__ kv_cat, int ldr, long long poff)
{
  const int s = blockIdx.x;
  const float* row = kv_raw + (long long)s * ldr;
  float v[2];
  float ss = 0.f;
#pragma unroll
  for (int k = 0; k < 2; k++) {
    const int c = threadIdx.x + (k << 8);
    const float t = row[c] + row[c + poff] + row[c + 2 * poff] + row[c + 3 * poff];
    v[k] = t; ss += t * t;
  }
  __shared__ float red[4];
  float ws_ = wave_sum(ss);
  if ((threadIdx.x & 63) == 0) red[threadIdx.x >> 6] = ws_;
  __syncthreads();
  const float inv = rsqrtf((red[0] + red[1] + red[2] + red[3]) / (float)KVL + EPS);
#pragma unroll
  for (int k = 0; k < 2; k++) {
    const int c = threadIdx.x + (k << 8);
    kv_cat[(long long)s * CAT + c] = __float2bfloat16(v[k] * inv * g[c]);
  }
  if (threadIdx.x < 64) {
    const int r = threadIdx.x;
    const int c = KVL + r;
    const float x = row[c] + row[c + poff] + row[c + 2 * poff] + row[c + 3 * poff];
    const float xp = __shfl_xor(x, 32, 64);
    const float rot = (r < 32) ? -xp : xp;
    kv_cat[(long long)s * CAT + KVL + r] =
        __float2bfloat16(x * cosp[s * ROPE + r] + rot * sinp[s * ROPE + r]);
  }
}

// ---------------------------------------------------------------------------
// MFMA flash attention v13 (verified R4-R14, ~82 us): key+value absorbed,
// head dim 192, cheap overflow-detect softmax, stage-before-compute +
// single __syncthreads skeleton.
// ---------------------------------------------------------------------------
__global__ __launch_bounds__(512, 2)
void attn_mfma13(const bf16* __restrict__ q2, const bf16* __restrict__ k2,
                 const bf16* __restrict__ kv_vT, bf16* __restrict__ ctx)
{
  __shared__ unsigned short kkl[2][32 * CAT2];  // 2 x 12,288 B  K tiles (swizzled)
  __shared__ unsigned short vtl[2][128 * 32];   // 2 x  8,192 B  V^T tiles (swizzled)
  __shared__ unsigned short ps[8][16][40];      // 10,240 B per-wave P transpose
  const int tid = threadIdx.x;
  const int bid = blockIdx.x;
  const int h  = bid & 31;
  const int qb = 15 - (bid >> 5);               // heavy blocks dispatched first
  const int w = tid >> 6, lane = tid & 63;
  const int l15 = lane & 15, g = lane >> 4;
  const int wq0 = qb * 128 + w * 16;
  const int rbase = g * 4;
  const float scale = 0.07216878364870322f;     // 1/sqrt(192)

  const bf16* ksrc[2];
#pragma unroll
  for (int j = 0; j < 2; j++) {
    const int f  = j * 512 + ((j == 1) ? (tid & 255) : tid);
    const int r  = f / 24;
    const int cg = ((f % 24) << 4) ^ ((r & 7) << 4);
    ksrc[j] = k2 + ((long long)h * S + r) * CAT2 + (cg >> 1);
  }
  const int vc = tid >> 2;
  const bf16* vsrc = kv_vT + (long long)h * VH * S + (long long)vc * S
                   + (((tid & 3) ^ ((vc >> 1) & 3)) * 8);

  auto stage = [&](int buf, int kbase) {
    gload16(ksrc[0] + (long long)kbase * CAT2, &kkl[buf][(w * 64) * 8]);
    if (tid < 256)
      gload16(ksrc[1] + (long long)kbase * CAT2, &kkl[buf][(512 + w * 64) * 8]);
    gload16(vsrc + kbase, &vtl[buf][(w * 64) * 8]);
  };

  s16x8 qf[6];
  const bf16* qp = q2 + ((long long)h * S + (wq0 + l15)) * CAT2 + g * 8;
#pragma unroll
  for (int ch = 0; ch < 6; ch++) qf[ch] = *(const s16x8*)(qp + ch * 32);

  s16x8 ones;
#pragma unroll
  for (int i = 0; i < 8; i++) ones[i] = (short)0x3F80;

  f32x4 acc[8];
#pragma unroll
  for (int nt = 0; nt < 8; nt++) acc[nt] = (f32x4){0.f, 0.f, 0.f, 0.f};
  f32x4 accl = (f32x4){0.f, 0.f, 0.f, 0.f};
  float mrow[4];
#pragma unroll
  for (int r = 0; r < 4; r++) mrow[r] = -3e38f;

  stage(0, 0);
  __syncthreads();

  const int ntb = 4 * qb + 4;
  int buf = 0;
  for (int t = 0; t < ntb; t++) {
    const int kbase = t * 32;
    if (t + 1 < ntb) stage(buf ^ 1, kbase + 32);   // overlap with compute(t)
    if (kbase <= wq0 + 15) {
      f32x4 st0 = (f32x4){0.f,0.f,0.f,0.f}, st1 = (f32x4){0.f,0.f,0.f,0.f};
      const unsigned short* kb0 = &kkl[buf][l15 * CAT2];
      const int rsw = (l15 & 7) << 4;
#pragma unroll
      for (int ch = 0; ch < 6; ch++) {
        const int cb = ((ch * 64 + g * 16) ^ rsw) >> 1;
        s16x8 b0 = *(const s16x8*)(kb0 + cb);
        s16x8 b1 = *(const s16x8*)(kb0 + 16 * CAT2 + cb);
        st0 = __builtin_amdgcn_mfma_f32_16x16x32_bf16(qf[ch], b0, st0, 0, 0, 0);
        st1 = __builtin_amdgcn_mfma_f32_16x16x32_bf16(qf[ch], b1, st1, 0, 0, 0);
      }
      float p0v[4], p1v[4];
      float pmax = 0.f;
#pragma unroll
      for (int r = 0; r < 4; r++) {
        const int qg = wq0 + rbase + r;
        const bool v0 = (kbase + l15) <= qg, v1 = (kbase + 16 + l15) <= qg;
        const float s0 = st0[r] * scale, s1 = st1[r] * scale;
        const float p0 = v0 ? __expf(s0 - mrow[r]) : 0.f;
        const float p1 = v1 ? __expf(s1 - mrow[r]) : 0.f;
        p0v[r] = p0; p1v[r] = p1;
        pmax = fmaxf(pmax, fmaxf(p0, p1));
      }
      if (__builtin_expect(__any(pmax > 2981.0f), 0)) {   // rare: growth > ~8
#pragma unroll
        for (int r = 0; r < 4; r++) {
          const int qg = wq0 + rbase + r;
          const bool v0 = (kbase + l15) <= qg, v1 = (kbase + 16 + l15) <= qg;
          const float s0 = st0[r] * scale, s1 = st1[r] * scale;
          float tmax = fmaxf(v0 ? s0 : -3e38f, v1 ? s1 : -3e38f);
#pragma unroll
          for (int off = 8; off; off >>= 1) tmax = fmaxf(tmax, __shfl_xor(tmax, off, 64));
          if (tmax > mrow[r] + 8.0f) {
            const float corr = __expf(mrow[r] - tmax);    // 0 on first tile
            mrow[r] = tmax;
#pragma unroll
            for (int nt = 0; nt < 8; nt++) acc[nt][r] *= corr;
            accl[r] *= corr;
            p0v[r] = v0 ? __expf(s0 - mrow[r]) : 0.f;
            p1v[r] = v1 ? __expf(s1 - mrow[r]) : 0.f;
          }
        }
      }
#pragma unroll
      for (int r = 0; r < 4; r++) {
        union { bf16 b; unsigned short u; } c0, c1;
        c0.b = __float2bfloat16(p0v[r]); c1.b = __float2bfloat16(p1v[r]);
        ps[w][rbase + r][l15]      = c0.u;
        ps[w][rbase + r][16 + l15] = c1.u;
      }
      asm volatile("" ::: "memory");   // order ps stores before reads (per-wave)
      s16x8 pa = *(const s16x8*)&ps[w][l15][g * 8];
      const unsigned short* vt = &vtl[buf][l15 * 32 + ((g * 8) ^ (((l15 >> 1) & 3) * 8))];
#pragma unroll
      for (int nt = 0; nt < 8; nt++) {
        s16x8 bv = *(const s16x8*)(vt + nt * 512);
        acc[nt] = __builtin_amdgcn_mfma_f32_16x16x32_bf16(pa, bv, acc[nt], 0, 0, 0);
      }
      accl = __builtin_amdgcn_mfma_f32_16x16x32_bf16(pa, ones, accl, 0, 0, 0);
    }
    __syncthreads();   // drains stage(t+1) loads + all waves done with buf
    buf ^= 1;
  }

#pragma unroll
  for (int r = 0; r < 4; r++) {
    const float inv = 1.f / accl[r];
    bf16* op = ctx + (long long)(wq0 + rbase + r) * (H * VH) + h * VH + l15;
#pragma unroll
    for (int nt = 0; nt < 8; nt++) op[nt * 16] = __float2bfloat16(acc[nt][r] * inv);
  }
}

// ---------------------------------------------------------------------------
extern "C" void kernel_launch(void* const* d_in, const int* in_sizes, int n_in,
                              void* d_out, int out_size, void* d_ws, size_t ws_size,
                              hipStream_t stream)
{
  const float* h2     = (const float*)d_in[0];
  const float* cosp   = (const float*)d_in[1];
  const float* sinp   = (const float*)d_in[2];
  const float* w_q_a  = (const float*)d_in[3];
  const float* g_q_a  = (const float*)d_in[4];
  const float* w_q_b  = (const float*)d_in[5];
  const float* w_kv_a = (const float*)d_in[6];
  const float* g_kv_a = (const float*)d_in[7];
  const float* w_uk_t = (const float*)d_in[8];
  const float* w_uv   = (const float*)d_in[9];
  const float* w_o    = (const float*)d_in[10];
  float* out = (float*)d_out;

  // ---- workspace layout (R14 base; k2 MOVED to Y+25.2MB so the fused
  //      dispatch's absorb writes don't race q_b's wqb_b reads) ----
  // Y liveness: hb [0..16.8M) dead after qkv; wcat_b [16.8..34.1M) dead after
  // qkv; wqb_b [0..18.9M) cast post-qkv, read by fused; q_a_bf [18.9..25.2M)
  // written by rmsnorm, read by fused; k2 [25.2..50.3M) written by fused,
  // read by attn; kv_vT [50.3..67.1M) written by fused, read by attn;
  // out_p1 [0..33.5M) written after attn (wqb_b/q_a_bf/k2-overlap all dead).
  char* ws = (char*)d_ws;
  bf16* wukb   = (bf16*)(ws);                          // 4,194,304  [H][NOPE][KVL]
  bf16* wuv_t  = (bf16*)(ws + 4194304);                // 4,194,304  [H][VH][KVL] (contiguous)
  bf16* kv_cat = (bf16*)(ws + 8388608);                // 2,359,296
  char* X = ws + 13107200;                             // 75,497,472
  char* Y = X + 75497472;                              // 67,108,864
  float* qkv_p = (float*)(X);                          // [4][2048][2112] f32 69,206,016
  bf16*  wo_b  = (bf16*)(X);                           // 33,554,432 (after rmsnorm+kvpost)
  bf16*  q2    = (bf16*)(X + 33554432);                // 25,165,824 (after rmsnorm+kvpost)
  bf16*  ctx   = (bf16*)(X + 58720256);                // 16,777,216 (attn output)
  bf16*  hb     = (bf16*)(Y);                          // 16,777,216 (dead after qkv GEMM)
  bf16*  wcat_b = (bf16*)(Y + 16777216);               // 17,301,504 (dead after qkv)
  bf16*  wqb_b  = (bf16*)(Y);                          // 18,874,368 (cast after qkv)
  bf16*  q_a_bf = (bf16*)(Y + 18874368);               // 6,291,456
  bf16*  k2     = (bf16*)(Y + 25165824);               // 25,165,824 (fused absorb+krope)
  bf16*  kv_vT  = (bf16*)(Y + 50331648);               // 16,777,216
  float* out_p1 = (float*)(Y);                         // 33,554,432 (after attn)

  // ---- early casts ----
  cast_kernel<<<1024, 256, 0, stream>>>(h2,     hb,     (long long)S * D / 4);
  cast_kernel<<<1024, 256, 0, stream>>>(w_q_a,  wcat_b, (long long)QL * D / 4);
  cast_kernel<<<1024, 256, 0, stream>>>(w_kv_a, wcat_b + (long long)QL * D, (long long)CAT * D / 4);
  cast_kernel<<<1024, 256, 0, stream>>>(w_uk_t, wukb,   (long long)H * NOPE * KVL / 4);
  tcast_kernel<<<dim3(VH / 32, KVL / 32, H), 256, 0, stream>>>(w_uv, wuv_t, KVL, VH);

  // 1+4 merged: qkv partials = hb @ wcat_b^T, mgemm3 256² K-split z=4 (verified)
  mgemm3<float><<<dim3(9, 8, 4), 512, 0, stream>>>(
      hb, wcat_b, qkv_p, qkv_p, nullptr, nullptr, S, NCAT, D / 4, D, D, NCAT,
      (long long)(D / 4), (long long)(D / 4), (long long)S * NCAT);
  // cast w_q_b (hb dead; region reused)
  cast_kernel<<<1024, 256, 0, stream>>>(w_q_b, wqb_b, (long long)H * QKH * QL / 4);
  // 2. rmsnorm over 4-partial sum -> q_a_bf
  rmsnorm_cast_kernel<<<dim3(S), 256, 0, stream>>>(
      qkv_p, g_q_a, q_a_bf, NCAT, (long long)S * NCAT);
  // 5. kv post over 4-partial sum -> kv_cat
  kvpost_kernel<<<dim3(S), 256, 0, stream>>>(
      qkv_p + QL, g_kv_a, cosp, sinp, kv_cat, NCAT, (long long)S * NCAT);
  // cast w_o (qkv_p dead after rmsnorm+kvpost)
  cast_kernel<<<1024, 256, 0, stream>>>(w_o, wo_b, (long long)D * H * VH / 4);
  // 3+6 + 5b+7 + 7b FUSED: q_b(rope) GEMM + ABSORB GEMM + krope in one
  // 512-block dispatch (fills the 64 CUs idle during q_b's 192 blocks)
  fused_qba<<<dim3(512), dim3(512), 0, stream>>>(
      q_a_bf, wqb_b, q2, kv_cat, (const bf16*)ws, k2, kv_vT, cosp, sinp);
  // 8. attention (verified v13) -> ctx bf16 [s][h*128+v]
  attn_mfma13<<<dim3(512), dim3(512), 0, stream>>>(q2, k2, kv_vT, ctx);
  // 10. out = ctx @ w_o^T -> f32, mgemm3 256² K-split z=2 (verified)
  const long long ooff = (long long)(out_p1 - out);
  mgemm3<float><<<dim3(16, 8, 2), 512, 0, stream>>>(
      ctx, wo_b, out, out, nullptr, nullptr, S, D, D / 2, D, D, D,
      (long long)(D / 2), (long long)(D / 2), ooff);
  // 10b. combine: out += out_p1
  add_kernel<<<1024, 256, 0, stream>>>(out, out_p1, (long long)S * D / 4);

  (void)in_sizes; (void)n_in; (void)out_size; (void)ws_size;
}